// Round 7
// baseline (56.234 us; speedup 1.0000x reference)
//
#include <hip/hip_runtime.h>
#include <math.h>

#define BB  4
#define KK  16
#define MSn 4096
#define NTn 16384
#define NCHUNK 128
#define CHUNK (MSn / NCHUNK)     // 32 sources per block
#define TT_   8                  // targets per thread
#define TGT_PER_BLK (256 * TT_)  // 2048 targets per block

// Kernel 1: val[b,m] = sigmoid(conv_b + sum_k w[k] * softmax_k(logits[b,:,m]))
// Also packs (s0,s1,s2,ss) per source into spack, and initializes the
// argmin key array to u64-max (replaces a separate memset dispatch).
__global__ __launch_bounds__(256) void sgg_val_kernel(
    const float* __restrict__ logits,  // [B,K,MS]
    const float* __restrict__ spos,    // [B,3,MS]
    const float* __restrict__ w,       // [1,K,1]
    const float* __restrict__ bias,    // [1]
    float* __restrict__ val,           // [B,MS]
    float4* __restrict__ spack,        // [B,MS]
    unsigned long long* __restrict__ keys)  // [B*NT]
{
    int i = blockIdx.x * 256 + threadIdx.x;   // [0, B*MS)
    int b = i >> 12;
    int m = i & (MSn - 1);
    const float* base = logits + (size_t)b * KK * MSn + m;

    // keys init: 16384 threads x 4 entries = 65536
    unsigned long long* kp = keys + (size_t)i * 4;
    kp[0] = ~0ull; kp[1] = ~0ull; kp[2] = ~0ull; kp[3] = ~0ull;

    float x[KK];
    float mx = -INFINITY;
#pragma unroll
    for (int k = 0; k < KK; ++k) {
        x[k] = base[(size_t)k * MSn];
        mx = fmaxf(mx, x[k]);
    }
    float sum = 0.f;
#pragma unroll
    for (int k = 0; k < KK; ++k) {
        x[k] = expf(x[k] - mx);
        sum += x[k];
    }
    float inv = 1.0f / sum;
    float acc = bias[0];
#pragma unroll
    for (int k = 0; k < KK; ++k) {
        acc += w[k] * (x[k] * inv);
    }
    val[i] = 1.0f / (1.0f + expf(-acc));

    const float* sp = spos + (size_t)b * 3 * MSn;
    float s0 = sp[m];
    float s1 = sp[MSn + m];
    float s2 = sp[2 * MSn + m];
    float ss = __fadd_rn(__fadd_rn(__fmul_rn(s0, s0), __fmul_rn(s1, s1)),
                         __fmul_rn(s2, s2));
    spack[i] = make_float4(s0, s1, s2, ss);
}

// Kernel 2: partial NN scan over a 32-source chunk, 8 targets/thread.
// __launch_bounds__(256,4): the (256,8) variant budgets only 32 arch-VGPRs
// (allocator budgets against a 256-reg pool) and spills TT_=8 state (R5:
// FETCH 228MB, 2.2x slowdown). (256,4) -> 64-reg budget, 36 used, no spill;
// 36 <= 64 still permits 8 waves/SIMD residency.
// Grid = 4096 blocks (NCHUNK=128): >= 2 residency rounds so early-finishing
// CUs backfill and the drain tail shrinks (R6 idle was 24% at exactly-one-
// round grid of 2048).
// Reference-exact d2 per candidate:
//   dot = (t0*s0 + t1*s1) + t2*s2
//   d2  = fma(-2,dot,tt) + ss     (bit-identical to (tt-(dot+dot))+ss,
//                                  since 2*dot is exactly representable)
// Strict < keeps first occurrence; cross-chunk merge via atomicMin on
// packed (monotone-key<<32 | global_m) -> equal d2 picks smaller m.
__global__ __launch_bounds__(256, 4) void sgg_nn_kernel(
    const float4* __restrict__ spack,  // [B,MS] (s0,s1,s2,ss)
    const float* __restrict__ tpos,    // [B,3,NT]
    unsigned long long* __restrict__ keys)  // [B*NT]
{
    int tg    = blockIdx.x >> 7;       // 32 target groups of 2048 targets
    int chunk = blockIdx.x & (NCHUNK - 1);
    int b     = tg >> 3;               // 8 target groups per batch
    int cbase = chunk * CHUNK;
    const float4* sq = spack + (size_t)b * MSn + cbase;

    const float* tp = tpos + (size_t)b * 3 * NTn;
    float T0[TT_], T1[TT_], T2[TT_], Q[TT_], DMIN[TT_];
    int   IMIN[TT_];
    int n0 = (tg & 7) * TGT_PER_BLK + threadIdx.x;    // within-batch target id
#pragma unroll
    for (int j = 0; j < TT_; ++j) {
        int n = n0 + j * 256;
        T0[j] = tp[n];
        T1[j] = tp[NTn + n];
        T2[j] = tp[2 * NTn + n];
        Q[j]  = __fadd_rn(__fadd_rn(__fmul_rn(T0[j], T0[j]), __fmul_rn(T1[j], T1[j])),
                          __fmul_rn(T2[j], T2[j]));
        DMIN[j] = INFINITY;
        IMIN[j] = 0;
    }

#pragma unroll 8
    for (int m = 0; m < CHUNK; ++m) {
        float4 sv = sq[m];             // uniform address -> scalar load
#pragma unroll
        for (int j = 0; j < TT_; ++j) {
            float dot = __fadd_rn(__fadd_rn(__fmul_rn(T0[j], sv.x),
                                            __fmul_rn(T1[j], sv.y)),
                                  __fmul_rn(T2[j], sv.z));
            float d2  = __fadd_rn(__builtin_fmaf(-2.0f, dot, Q[j]), sv.w);
            bool  lt  = d2 < DMIN[j];            // strict <: first occurrence
            IMIN[j] = lt ? m : IMIN[j];          // m inline-const (0..31)
            DMIN[j] = lt ? d2 : DMIN[j];
        }
    }

#pragma unroll
    for (int j = 0; j < TT_; ++j) {
        unsigned int u = __float_as_uint(DMIN[j]);
        unsigned int k = (u & 0x80000000u) ? ~u : (u | 0x80000000u);
        unsigned long long p =
            ((unsigned long long)k << 32) | (unsigned int)(cbase + IMIN[j]);
        atomicMin(&keys[(size_t)b * NTn + n0 + j * 256], p);
    }
}

// Kernel 3: out[b,n] = val[b, argmin_m]
__global__ __launch_bounds__(256) void sgg_out_kernel(
    const unsigned long long* __restrict__ keys,
    const float* __restrict__ val,
    float* __restrict__ out)
{
    int n = blockIdx.x * 256 + threadIdx.x;    // [0, B*NT)
    int b = n >> 14;
    unsigned int m = (unsigned int)keys[n];    // low 32 bits = global m
    out[n] = val[b * MSn + m];
}

extern "C" void kernel_launch(void* const* d_in, const int* in_sizes, int n_in,
                              void* d_out, int out_size, void* d_ws, size_t ws_size,
                              hipStream_t stream) {
    const float* sem  = (const float*)d_in[0];  // [4,16,4096]
    const float* spos = (const float*)d_in[1];  // [4,3,4096]
    const float* tpos = (const float*)d_in[2];  // [4,3,16384]
    const float* w    = (const float*)d_in[3];  // [1,16,1]
    const float* bias = (const float*)d_in[4];  // [1]
    float* out = (float*)d_out;                 // [4,1,16384]

    unsigned long long* keys = (unsigned long long*)d_ws;              // 512 KB
    float*  val   = (float*)((char*)d_ws + (size_t)BB * NTn * 8);      // 64 KB
    float4* spack = (float4*)((char*)d_ws + (size_t)BB * NTn * 8
                                          + (size_t)BB * MSn * 4);     // 256 KB

    sgg_val_kernel<<<(BB * MSn) / 256, 256, 0, stream>>>(sem, spos, w, bias, val, spack, keys);
    sgg_nn_kernel<<<(BB * NTn / TGT_PER_BLK) * NCHUNK, 256, 0, stream>>>(spack, tpos, keys);
    sgg_out_kernel<<<(BB * NTn) / 256, 256, 0, stream>>>(keys, val, out);
}

// Round 8
// 55.104 us; speedup vs baseline: 1.0205x; 1.0205x over previous
//
#include <hip/hip_runtime.h>
#include <math.h>

#define BB  4
#define KK  16
#define MSn 4096
#define NTn 16384
#define NCHUNK 64
#define CHUNK (MSn / NCHUNK)     // 64 sources per block
#define TT_   8                  // targets per thread
#define TGT_PER_BLK (256 * TT_)  // 2048 targets per block

// Kernel 1: val[b,m] = sigmoid(conv_b + sum_k w[k] * softmax_k(logits[b,:,m]))
// Also packs (s0,s1,s2,ss) per source into spack, and initializes the
// argmin key array to u64-max (replaces a separate memset dispatch).
__global__ __launch_bounds__(256) void sgg_val_kernel(
    const float* __restrict__ logits,  // [B,K,MS]
    const float* __restrict__ spos,    // [B,3,MS]
    const float* __restrict__ w,       // [1,K,1]
    const float* __restrict__ bias,    // [1]
    float* __restrict__ val,           // [B,MS]
    float4* __restrict__ spack,        // [B,MS]
    unsigned long long* __restrict__ keys)  // [B*NT]
{
    int i = blockIdx.x * 256 + threadIdx.x;   // [0, B*MS)
    int b = i >> 12;
    int m = i & (MSn - 1);
    const float* base = logits + (size_t)b * KK * MSn + m;

    // keys init: 16384 threads x 4 entries = 65536
    unsigned long long* kp = keys + (size_t)i * 4;
    kp[0] = ~0ull; kp[1] = ~0ull; kp[2] = ~0ull; kp[3] = ~0ull;

    float x[KK];
    float mx = -INFINITY;
#pragma unroll
    for (int k = 0; k < KK; ++k) {
        x[k] = base[(size_t)k * MSn];
        mx = fmaxf(mx, x[k]);
    }
    float sum = 0.f;
#pragma unroll
    for (int k = 0; k < KK; ++k) {
        x[k] = expf(x[k] - mx);
        sum += x[k];
    }
    float inv = 1.0f / sum;
    float acc = bias[0];
#pragma unroll
    for (int k = 0; k < KK; ++k) {
        acc += w[k] * (x[k] * inv);
    }
    val[i] = 1.0f / (1.0f + expf(-acc));

    const float* sp = spos + (size_t)b * 3 * MSn;
    float s0 = sp[m];
    float s1 = sp[MSn + m];
    float s2 = sp[2 * MSn + m];
    float ss = __fadd_rn(__fadd_rn(__fmul_rn(s0, s0), __fmul_rn(s1, s1)),
                         __fmul_rn(s2, s2));
    spack[i] = make_float4(s0, s1, s2, ss);
}

// Kernel 2: partial NN scan over a 64-source chunk, 8 targets/thread.
// R6 config (measured best: 51.6us, VALUBusy 76%) + wave desync stagger.
// Theory: the ~24% issue-idle is waves stalling in lockstep on the same
// per-batch s_waitcnt lgkmcnt(0) (SMEM waits are all-or-nothing). A
// per-wave staggered s_sleep at entry offsets the stall phases so other
// waves cover each stall. Stalls are fixed-latency -> offsets persist.
// __launch_bounds__(256,4): (256,8) clamps to 32 arch-VGPRs and spills
// TT_=8 state (R5: FETCH 228MB, 2.2x slowdown).
// Reference-exact d2 per candidate:
//   dot = (t0*s0 + t1*s1) + t2*s2
//   d2  = fma(-2,dot,tt) + ss     (bit-identical to (tt-(dot+dot))+ss,
//                                  since 2*dot is exactly representable)
// Strict < keeps first occurrence; cross-chunk merge via atomicMin on
// packed (monotone-key<<32 | global_m) -> equal d2 picks smaller m.
__global__ __launch_bounds__(256, 4) void sgg_nn_kernel(
    const float4* __restrict__ spack,  // [B,MS] (s0,s1,s2,ss)
    const float* __restrict__ tpos,    // [B,3,NT]
    unsigned long long* __restrict__ keys)  // [B*NT]
{
    // Desync the block's 4 waves: wave w sleeps ~w*256 cycles.
    {
        int wid = threadIdx.x >> 6;
        for (int i = 0; i < wid; ++i) __builtin_amdgcn_s_sleep(4);
    }

    int tg    = blockIdx.x >> 6;       // 32 target groups of 2048 targets
    int chunk = blockIdx.x & (NCHUNK - 1);
    int b     = tg >> 3;               // 8 target groups per batch
    int cbase = chunk * CHUNK;
    const float4* sq = spack + (size_t)b * MSn + cbase;

    const float* tp = tpos + (size_t)b * 3 * NTn;
    float T0[TT_], T1[TT_], T2[TT_], Q[TT_], DMIN[TT_];
    int   IMIN[TT_];
    int n0 = (tg & 7) * TGT_PER_BLK + threadIdx.x;    // within-batch target id
#pragma unroll
    for (int j = 0; j < TT_; ++j) {
        int n = n0 + j * 256;
        T0[j] = tp[n];
        T1[j] = tp[NTn + n];
        T2[j] = tp[2 * NTn + n];
        Q[j]  = __fadd_rn(__fadd_rn(__fmul_rn(T0[j], T0[j]), __fmul_rn(T1[j], T1[j])),
                          __fmul_rn(T2[j], T2[j]));
        DMIN[j] = INFINITY;
        IMIN[j] = 0;
    }

#pragma unroll 8
    for (int m = 0; m < CHUNK; ++m) {
        float4 sv = sq[m];             // uniform address -> scalar load
#pragma unroll
        for (int j = 0; j < TT_; ++j) {
            float dot = __fadd_rn(__fadd_rn(__fmul_rn(T0[j], sv.x),
                                            __fmul_rn(T1[j], sv.y)),
                                  __fmul_rn(T2[j], sv.z));
            float d2  = __fadd_rn(__builtin_fmaf(-2.0f, dot, Q[j]), sv.w);
            bool  lt  = d2 < DMIN[j];            // strict <: first occurrence
            IMIN[j] = lt ? m : IMIN[j];          // m inline-const (0..63)
            DMIN[j] = lt ? d2 : DMIN[j];
        }
    }

#pragma unroll
    for (int j = 0; j < TT_; ++j) {
        unsigned int u = __float_as_uint(DMIN[j]);
        unsigned int k = (u & 0x80000000u) ? ~u : (u | 0x80000000u);
        unsigned long long p =
            ((unsigned long long)k << 32) | (unsigned int)(cbase + IMIN[j]);
        atomicMin(&keys[(size_t)b * NTn + n0 + j * 256], p);
    }
}

// Kernel 3: out[b,n] = val[b, argmin_m]
__global__ __launch_bounds__(256) void sgg_out_kernel(
    const unsigned long long* __restrict__ keys,
    const float* __restrict__ val,
    float* __restrict__ out)
{
    int n = blockIdx.x * 256 + threadIdx.x;    // [0, B*NT)
    int b = n >> 14;
    unsigned int m = (unsigned int)keys[n];    // low 32 bits = global m
    out[n] = val[b * MSn + m];
}

extern "C" void kernel_launch(void* const* d_in, const int* in_sizes, int n_in,
                              void* d_out, int out_size, void* d_ws, size_t ws_size,
                              hipStream_t stream) {
    const float* sem  = (const float*)d_in[0];  // [4,16,4096]
    const float* spos = (const float*)d_in[1];  // [4,3,4096]
    const float* tpos = (const float*)d_in[2];  // [4,3,16384]
    const float* w    = (const float*)d_in[3];  // [1,16,1]
    const float* bias = (const float*)d_in[4];  // [1]
    float* out = (float*)d_out;                 // [4,1,16384]

    unsigned long long* keys = (unsigned long long*)d_ws;              // 512 KB
    float*  val   = (float*)((char*)d_ws + (size_t)BB * NTn * 8);      // 64 KB
    float4* spack = (float4*)((char*)d_ws + (size_t)BB * NTn * 8
                                          + (size_t)BB * MSn * 4);     // 256 KB

    sgg_val_kernel<<<(BB * MSn) / 256, 256, 0, stream>>>(sem, spos, w, bias, val, spack, keys);
    sgg_nn_kernel<<<(BB * NTn / TGT_PER_BLK) * NCHUNK, 256, 0, stream>>>(spack, tpos, keys);
    sgg_out_kernel<<<(BB * NTn) / 256, 256, 0, stream>>>(keys, val, out);
}